// Round 15
// baseline (118.398 us; speedup 1.0000x reference)
//
#include <hip/hip_runtime.h>
#include <stdint.h>
#include <math.h>

// Soft-DTW forward, B=64, N=M=512, gamma=1 — probability-domain wavefront DP,
// SINGLE-WAVE-PER-BATCH design (round 15).
//
// P = exp(-R): P_new = exp(-d)*(Pa+Pb+Pc). Lane l of the block's ONE wave owns
// DP rows 8l+1..8l+8 (the whole 512-row batch in one wave). At step t, lane l
// computes col c = t-l for its 8 rows (8 chained fma cells). Row handoff
// between lanes via DPP wave_shr:1 on x[7] (+ rsc scale reconcile); the DPP
// bound_ctrl zero IS the exact P(R[0][*])=0 top boundary for lane 0.
// -> NO barriers, NO inter-wave LDS handoff, NO bnd/bndE: the multi-wave
// chunk skeleton (whose ~3000cy/chunk wait floor survived rounds 6-14's
// math/scratch/vmcnt/TA/LDS fixes) is eliminated structurally.
//
// D delivery: R10's coalesced stage (16x buffer_load_dwordx4 per 8-col block,
// 32 rows x 8 cols per instr) -> v_cvt_pk_bf16_f32 -> wave-private LDS ring,
// re-laid-out per-lane-contiguous: word addr = 521*l + 65*r + m (m = ring
// word of col pair, 64-word/128-col ring). Read banks = (9l + r + m) % 32:
// 9 odd -> full 32-bank spread = conflict-free. Writes: 2x b32 (odd lane
// stride makes b64 unaligned), ~2-way. Per-lane scale E + per-group renorm
// (identical numerics to the verified R10/R14 kernel).
//
// 64 blocks x 64 threads; LDS 133,376B -> 1 block/CU; 64 CUs.

namespace {
constexpr int NG = 72;   // 72 groups x 8 steps = 576 >= 575 needed
constexpr int LS = 521;  // lane stride in ring dwords (8 rows x 65 + 1)
constexpr float LN2 = 0.69314718055994530942f;
constexpr float L2E = 1.44269504088896340736f;
}

using f4 = __attribute__((ext_vector_type(4))) float;
using u32x4 = __attribute__((ext_vector_type(4))) unsigned int;

__device__ __forceinline__ float dpp_shr1(float v) {
  // lane n <- lane n-1 (wave_shr:1); lane 0 reads 0 (bound_ctrl) = P(INF) = 0
  return __int_as_float(__builtin_amdgcn_update_dpp(0, __float_as_int(v), 0x138, 0xf, 0xf, true));
}
__device__ __forceinline__ int dpp_shr1_i(int v) {
  return __builtin_amdgcn_update_dpp(0, v, 0x138, 0xf, 0xf, true);
}
__device__ __forceinline__ int imax(int a, int b) { return a > b ? a : b; }

// pack 4 f32 -> 2 u32 of 2 bf16 (RNE); low half = first operand (even col)
__device__ __forceinline__ void packw2(const f4& g, uint32_t& a, uint32_t& b) {
  asm("v_cvt_pk_bf16_f32 %0, %1, %2" : "=v"(a) : "v"(g[0]), "v"(g[1]));
  asm("v_cvt_pk_bf16_f32 %0, %1, %2" : "=v"(b) : "v"(g[2]), "v"(g[3]));
}

// 8 DP steps (one group). G = guarded (fill/drain) variant.
// Wr[r][k]: bf16 ring words for D row 8l+r, ring words k0..k0+4.
// Step s: even s -> word s>>1, shift shE; odd s -> word (s+par)>>1, shift shO.
template <bool G>
__device__ __forceinline__ void steps8(const uint32_t (&Wr)[8][5], int t0, int l,
                                       bool par, uint32_t shE, uint32_t shO,
                                       float rsc, float (&x)[8], float& areg) {
#pragma unroll
  for (int s = 0; s < 8; ++s) {
    // bb = up-row value for row 8l+1 = lane l-1's x[7] (pre-step), rescaled.
    const float bsh = dpp_shr1(x[7]) * rsc;
    float aa = areg;
    int c = 0;
    bool act = true;
    if (G) {
      c = t0 + s - l;
      aa = (l == 0 && c == 0) ? 1.0f : aa;  // P(R[0][0]=0)=1 seed for cell (1,1)
      act = ((unsigned)c < 512u);
    }
    float po = aa;   // P[row-1][c-1] (diag)
    float pn = bsh;  // P[row-1][c]   (up)
#pragma unroll
    for (int r = 0; r < 8; ++r) {
      uint32_t w;
      if ((s & 1) == 0) w = Wr[r][s >> 1];
      else              w = par ? Wr[r][(s + 1) >> 1] : Wr[r][s >> 1];
      const uint32_t sh = (s & 1) ? shO : shE;
      const float d = __uint_as_float((w << sh) & 0xffff0000u);
      const float k = __builtin_amdgcn_exp2f(d * -L2E);   // exp(-d), off-chain
      const float xo = x[r];
      const float xn = fmaf(k, pn, k * (po + xo));  // k*(diag + left + up)
      po = xo;  // next row's diag = this row's old (col c-1) value
      pn = xn;  // next row's up   = this row's new value
      if (G) x[r] = act ? xn : xo;
      else   x[r] = xn;
    }
    areg = bsh;  // next step's diag for row 8l+1
  }
}

// Coalesced stage of col-block [CS, CS+8) for all 512 rows:
// instr i, lane j: row 32i+(j>>1), 16B at col CS+4*(j&1) -> 32 lines/instr.
#define ISSUE(CS) do {                                                              \
    const int vo_ = voBase + ((CS) << 2);                                           \
    asm volatile("buffer_load_dwordx4 %0, %1, %2, 0 offen" : "=v"(s0)  : "v"(vo_), "s"(srd));              \
    asm volatile("buffer_load_dwordx4 %0, %1, %2, 0 offen" : "=v"(s1)  : "v"(vo_ + 1*65536), "s"(srd));    \
    asm volatile("buffer_load_dwordx4 %0, %1, %2, 0 offen" : "=v"(s2)  : "v"(vo_ + 2*65536), "s"(srd));    \
    asm volatile("buffer_load_dwordx4 %0, %1, %2, 0 offen" : "=v"(s3)  : "v"(vo_ + 3*65536), "s"(srd));    \
    asm volatile("buffer_load_dwordx4 %0, %1, %2, 0 offen" : "=v"(s4)  : "v"(vo_ + 4*65536), "s"(srd));    \
    asm volatile("buffer_load_dwordx4 %0, %1, %2, 0 offen" : "=v"(s5)  : "v"(vo_ + 5*65536), "s"(srd));    \
    asm volatile("buffer_load_dwordx4 %0, %1, %2, 0 offen" : "=v"(s6)  : "v"(vo_ + 6*65536), "s"(srd));    \
    asm volatile("buffer_load_dwordx4 %0, %1, %2, 0 offen" : "=v"(s7)  : "v"(vo_ + 7*65536), "s"(srd));    \
    asm volatile("buffer_load_dwordx4 %0, %1, %2, 0 offen" : "=v"(s8)  : "v"(vo_ + 8*65536), "s"(srd));    \
    asm volatile("buffer_load_dwordx4 %0, %1, %2, 0 offen" : "=v"(s9)  : "v"(vo_ + 9*65536), "s"(srd));    \
    asm volatile("buffer_load_dwordx4 %0, %1, %2, 0 offen" : "=v"(s10) : "v"(vo_ + 10*65536), "s"(srd));   \
    asm volatile("buffer_load_dwordx4 %0, %1, %2, 0 offen" : "=v"(s11) : "v"(vo_ + 11*65536), "s"(srd));   \
    asm volatile("buffer_load_dwordx4 %0, %1, %2, 0 offen" : "=v"(s12) : "v"(vo_ + 12*65536), "s"(srd));   \
    asm volatile("buffer_load_dwordx4 %0, %1, %2, 0 offen" : "=v"(s13) : "v"(vo_ + 13*65536), "s"(srd));   \
    asm volatile("buffer_load_dwordx4 %0, %1, %2, 0 offen" : "=v"(s14) : "v"(vo_ + 14*65536), "s"(srd));   \
    asm volatile("buffer_load_dwordx4 %0, %1, %2, 0 offen" : "=v"(s15) : "v"(vo_ + 15*65536), "s"(srd));   \
} while (0)

// vmcnt(0) safe: the 16 stage loads are the only in-flight VMEM.
// Target row R=32i+(j>>1): owner lane L=R>>3, local row r=R&7.
// Byte addr = 2084*L + 260*r + 4*m0 + 8*(j&1)  (wconst_j holds the j-parts).
// Two b32 stores per f4 (odd lane stride -> b64 would be 4B-misaligned).
#define WRITEB(CS) do {                                                             \
    asm volatile("s_waitcnt vmcnt(0)"                                               \
        : "+v"(s0), "+v"(s1), "+v"(s2), "+v"(s3), "+v"(s4), "+v"(s5), "+v"(s6),     \
          "+v"(s7), "+v"(s8), "+v"(s9), "+v"(s10), "+v"(s11), "+v"(s12),            \
          "+v"(s13), "+v"(s14), "+v"(s15)::);                                       \
    uint32_t* wp_ = (uint32_t*)((char*)&ring[0] + wconst + ((((CS) >> 1) & 63) << 2)); \
    uint32_t a_, b_;                                                                \
    packw2(s0,  a_, b_); wp_[0*2084]     = a_; wp_[0*2084 + 1]     = b_;            \
    packw2(s1,  a_, b_); wp_[1*2084/4*0 + 2084/4*0 + 2084*0 + 521*4]   = a_; wp_[521*4 + 1] = b_; \
    packw2(s2,  a_, b_); wp_[521*8]      = a_; wp_[521*8 + 1]      = b_;            \
    packw2(s3,  a_, b_); wp_[521*12]     = a_; wp_[521*12 + 1]     = b_;            \
    packw2(s4,  a_, b_); wp_[521*16]     = a_; wp_[521*16 + 1]     = b_;            \
    packw2(s5,  a_, b_); wp_[521*20]     = a_; wp_[521*20 + 1]     = b_;            \
    packw2(s6,  a_, b_); wp_[521*24]     = a_; wp_[521*24 + 1]     = b_;            \
    packw2(s7,  a_, b_); wp_[521*28]     = a_; wp_[521*28 + 1]     = b_;            \
    packw2(s8,  a_, b_); wp_[521*32]     = a_; wp_[521*32 + 1]     = b_;            \
    packw2(s9,  a_, b_); wp_[521*36]     = a_; wp_[521*36 + 1]     = b_;            \
    packw2(s10, a_, b_); wp_[521*40]     = a_; wp_[521*40 + 1]     = b_;            \
    packw2(s11, a_, b_); wp_[521*44]     = a_; wp_[521*44 + 1]     = b_;            \
    packw2(s12, a_, b_); wp_[521*48]     = a_; wp_[521*48 + 1]     = b_;            \
    packw2(s13, a_, b_); wp_[521*52]     = a_; wp_[521*52 + 1]     = b_;            \
    packw2(s14, a_, b_); wp_[521*56]     = a_; wp_[521*56 + 1]     = b_;            \
    packw2(s15, a_, b_); wp_[521*60]     = a_; wp_[521*60 + 1]     = b_;            \
} while (0)

__global__ __launch_bounds__(64, 1) void sdtw_kernel(const float* __restrict__ D,
                                                     float* __restrict__ out) {
  __shared__ uint32_t ring[64 * LS + 4];  // per-lane bf16 ring: 521 dwords/lane
  const int l = threadIdx.x;              // single wave: lane = 8-row strip
  const int b = blockIdx.x;

  u32x4 srd;  // raw buffer descriptor over D (OOB -> 0, never faults)
  const uint64_t base = (uint64_t)(const void*)D;
  srd[0] = (unsigned)base;
  srd[1] = (unsigned)(base >> 32) & 0xffffu;  // stride=0
  srd[2] = 64u * 512u * 512u * 4u;            // num_records (bytes)
  srd[3] = 0x00020000u;

  const bool par = (l & 1) != 0;
  const uint32_t shE = par ? 0u : 16u;
  const uint32_t shO = par ? 16u : 0u;
  // stage load base: row (l>>1) part + col-sub (l&1)*4, batch b
  const int voBase = (b << 20) + ((l >> 1) << 11) + ((l & 1) << 4);
  // stage write base (byte): 2084*(l>>4) + 260*((l>>1)&7) + 8*(l&1)
  const int wconst = 2084 * (l >> 4) + 260 * ((l >> 1) & 7) + 8 * (l & 1);
  const uint32_t* __restrict__ rb = &ring[LS * l];

  float x[8] = {0, 0, 0, 0, 0, 0, 0, 0};  // P(left boundary INF) = 0
  float areg = 0.0f;                      // diag input for row 8l+1
  int E = 0;                              // per-lane scale exponent

  f4 s0, s1, s2, s3, s4, s5, s6, s7, s8, s9, s10, s11, s12, s13, s14, s15;

  // prologue: stage cols [0,8)
  ISSUE(0);
  WRITEB(0);

  for (int g = 0; g < NG; ++g) {
    const int t0 = 8 * g;
    const bool doStage = (g <= 62);  // stages cols [t0+8, t0+16)
    if (doStage) ISSUE(t0 + 8);

    // ring reads: 5 words x 8 rows covering cols [t0-l, t0-l+8]
    const int k0 = ((t0 - l) >> 1) & 63;  // arith shift: correct mod-128 ring idx
    uint32_t Wr[8][5];
#pragma unroll
    for (int k = 0; k < 5; ++k) {
      const int m = (k0 + k) & 63;
#pragma unroll
      for (int r = 0; r < 8; ++r) Wr[r][k] = rb[65 * r + m];
    }

    // per-lane scale maintenance (wave-local only)
    const int En = dpp_shr1_i(E);
    if ((x[0] == 0.0f) && (l != 0)) E = En;  // inactive: track left neighbor
    int dE = En - E;
    dE = dE < -126 ? -126 : (dE > 126 ? 126 : dE);
    const float rsc = __int_as_float((127 + dE) << 23);

    if (g < 8 || g >= 64)
      steps8<true>(Wr, t0, l, par, shE, shO, rsc, x, areg);
    else
      steps8<false>(Wr, t0, l, par, shE, shO, rsc, x, areg);

    // per-lane renorm: recenter max exponent to 2^-10
    int ex = 0;
#pragma unroll
    for (int r = 0; r < 8; ++r) ex = imax(ex, (__float_as_int(x[r]) >> 23) & 255);
    int sh = (ex > 0) ? (117 - ex) : 0;
    sh = sh < -110 ? -110 : sh;
    const float sc = __int_as_float((127 + sh) << 23);
#pragma unroll
    for (int r = 0; r < 8; ++r) x[r] *= sc;
    areg *= sc;
    E -= sh;

    if (doStage) WRITEB(t0 + 8);
  }

  if (l == 63) {
    // x[7] * 2^E = exp(-R[512][512]);  v_log_f32 is log2
    const float Rv = -(__builtin_amdgcn_logf(x[7]) + (float)E);
    out[b] = Rv * LN2;
  }
}

extern "C" void kernel_launch(void* const* d_in, const int* in_sizes, int n_in,
                              void* d_out, int out_size, void* d_ws, size_t ws_size,
                              hipStream_t stream) {
  const float* D = (const float*)d_in[0];
  float* out = (float*)d_out;
  hipLaunchKernelGGL(sdtw_kernel, dim3(64), dim3(64), 0, stream, D, out);
}

// Round 18
// 117.585 us; speedup vs baseline: 1.0069x; 1.0069x over previous
//
#include <hip/hip_runtime.h>
#include <stdint.h>
#include <math.h>

// Soft-DTW forward, B=64, N=M=512, gamma=1 — probability-domain wavefront DP,
// single-wave-per-batch (R15 structure, verified absmax 0.0).
//
// ROUND 18 DELTA (load-addressing only; math/ring/guards bit-identical):
// R15's stage loads touched 512 cache lines per group (32 lines/instr, each
// 64B line touched twice across groups for 32B each) — at ~64 outstanding
// lines/CU and ~300cy L2/L3 service that is ~2400cy/group of delivery, the
// measured floor. Now staged at FULL-LINE granularity: 16-col blocks, split
// into row-halves (rows 0..255 / 256..511) on alternating groups. 16 instr
// x 16 lines = 256 lines/group, every byte consumed in one touch. Same 16
// f4 registers, same ISSUE-top -> WRITEB-bottom vmcnt(0) lifetime (R15's
// proven pattern), same ring layout, reads, guards, scale machinery.
//
// 64 blocks x 64 threads (1 wave); lane l owns DP rows 8l+1..8l+8; DPP
// wave_shr row handoff (bound_ctrl 0 = exact top boundary); per-lane scale E.

namespace {
constexpr int NG = 72;   // 72 groups x 8 steps = 576 >= 575 needed
constexpr int LS = 521;  // lane stride in ring dwords (8 rows x 65 + 1)
constexpr float LN2 = 0.69314718055994530942f;
constexpr float L2E = 1.44269504088896340736f;
}

using f4 = __attribute__((ext_vector_type(4))) float;
using u32x4 = __attribute__((ext_vector_type(4))) unsigned int;

__device__ __forceinline__ float dpp_shr1(float v) {
  // lane n <- lane n-1 (wave_shr:1); lane 0 reads 0 (bound_ctrl) = P(INF) = 0
  return __int_as_float(__builtin_amdgcn_update_dpp(0, __float_as_int(v), 0x138, 0xf, 0xf, true));
}
__device__ __forceinline__ int dpp_shr1_i(int v) {
  return __builtin_amdgcn_update_dpp(0, v, 0x138, 0xf, 0xf, true);
}
__device__ __forceinline__ int imax(int a, int b) { return a > b ? a : b; }

// pack 4 f32 -> 2 u32 of 2 bf16 (RNE); low half = first operand (even col)
__device__ __forceinline__ void packw2(const f4& g, uint32_t& a, uint32_t& b) {
  asm("v_cvt_pk_bf16_f32 %0, %1, %2" : "=v"(a) : "v"(g[0]), "v"(g[1]));
  asm("v_cvt_pk_bf16_f32 %0, %1, %2" : "=v"(b) : "v"(g[2]), "v"(g[3]));
}

// 8 DP steps (one group). G = guarded (fill/drain) variant. (R15 verbatim.)
template <bool G>
__device__ __forceinline__ void steps8(const uint32_t (&Wr)[8][5], int t0, int l,
                                       bool par, uint32_t shE, uint32_t shO,
                                       float rsc, float (&x)[8], float& areg) {
#pragma unroll
  for (int s = 0; s < 8; ++s) {
    const float bsh = dpp_shr1(x[7]) * rsc;  // up-row for row 8l+1, rescaled
    float aa = areg;
    int c = 0;
    bool act = true;
    if (G) {
      c = t0 + s - l;
      aa = (l == 0 && c == 0) ? 1.0f : aa;  // P(R[0][0]=0)=1 seed for cell (1,1)
      act = ((unsigned)c < 512u);
    }
    float po = aa;   // P[row-1][c-1] (diag)
    float pn = bsh;  // P[row-1][c]   (up)
#pragma unroll
    for (int r = 0; r < 8; ++r) {
      uint32_t w;
      if ((s & 1) == 0) w = Wr[r][s >> 1];
      else              w = par ? Wr[r][(s + 1) >> 1] : Wr[r][s >> 1];
      const uint32_t sh = (s & 1) ? shO : shE;
      const float d = __uint_as_float((w << sh) & 0xffff0000u);
      const float k = __builtin_amdgcn_exp2f(d * -L2E);   // exp(-d), off-chain
      const float xo = x[r];
      const float xn = fmaf(k, pn, k * (po + xo));  // k*(diag + left + up)
      po = xo;
      pn = xn;
      if (G) x[r] = act ? xn : xo;
      else   x[r] = xn;
    }
    areg = bsh;
  }
}

// Full-line stage of col-block [CS, CS+16) for 256 rows (half HOFF):
// instr i, lane j: row 16i+(j>>2), 16B at col CS+4*(j&3) -> 4 lanes/64B line,
// 16 lines per instruction, every byte consumed.
#define ISSUE(CS, HOFF) do {                                                        \
    const int vo_ = voBase + (HOFF) + ((CS) << 2);                                  \
    asm volatile("buffer_load_dwordx4 %0, %1, %2, 0 offen" : "=v"(s0)  : "v"(vo_), "s"(srd));              \
    asm volatile("buffer_load_dwordx4 %0, %1, %2, 0 offen" : "=v"(s1)  : "v"(vo_ + 1*32768), "s"(srd));    \
    asm volatile("buffer_load_dwordx4 %0, %1, %2, 0 offen" : "=v"(s2)  : "v"(vo_ + 2*32768), "s"(srd));    \
    asm volatile("buffer_load_dwordx4 %0, %1, %2, 0 offen" : "=v"(s3)  : "v"(vo_ + 3*32768), "s"(srd));    \
    asm volatile("buffer_load_dwordx4 %0, %1, %2, 0 offen" : "=v"(s4)  : "v"(vo_ + 4*32768), "s"(srd));    \
    asm volatile("buffer_load_dwordx4 %0, %1, %2, 0 offen" : "=v"(s5)  : "v"(vo_ + 5*32768), "s"(srd));    \
    asm volatile("buffer_load_dwordx4 %0, %1, %2, 0 offen" : "=v"(s6)  : "v"(vo_ + 6*32768), "s"(srd));    \
    asm volatile("buffer_load_dwordx4 %0, %1, %2, 0 offen" : "=v"(s7)  : "v"(vo_ + 7*32768), "s"(srd));    \
    asm volatile("buffer_load_dwordx4 %0, %1, %2, 0 offen" : "=v"(s8)  : "v"(vo_ + 8*32768), "s"(srd));    \
    asm volatile("buffer_load_dwordx4 %0, %1, %2, 0 offen" : "=v"(s9)  : "v"(vo_ + 9*32768), "s"(srd));    \
    asm volatile("buffer_load_dwordx4 %0, %1, %2, 0 offen" : "=v"(s10) : "v"(vo_ + 10*32768), "s"(srd));   \
    asm volatile("buffer_load_dwordx4 %0, %1, %2, 0 offen" : "=v"(s11) : "v"(vo_ + 11*32768), "s"(srd));   \
    asm volatile("buffer_load_dwordx4 %0, %1, %2, 0 offen" : "=v"(s12) : "v"(vo_ + 12*32768), "s"(srd));   \
    asm volatile("buffer_load_dwordx4 %0, %1, %2, 0 offen" : "=v"(s13) : "v"(vo_ + 13*32768), "s"(srd));   \
    asm volatile("buffer_load_dwordx4 %0, %1, %2, 0 offen" : "=v"(s14) : "v"(vo_ + 14*32768), "s"(srd));   \
    asm volatile("buffer_load_dwordx4 %0, %1, %2, 0 offen" : "=v"(s15) : "v"(vo_ + 15*32768), "s"(srd));   \
} while (0)

// vmcnt(0) safe: the 16 stage loads are the only in-flight VMEM (R15 pattern).
// Row R = 16i+(l>>2) (+256 if B-half): owner lane L=R>>3=2i+(l>>5)(+32),
// local row r=(l>>2)&7, ring pair m0=((CS>>1)&63)+2*(l&3) (no wrap: CS%16==0).
// Byte addr = 2084*L + 260*r + 4*m0 -> wconst(l-parts) + 4168*i + LH + blk.
// Two b32 stores per f4 (odd 521-dword lane stride -> b64 misaligned).
#define WRITEB(CS, LH) do {                                                         \
    asm volatile("s_waitcnt vmcnt(0)"                                               \
        : "+v"(s0), "+v"(s1), "+v"(s2), "+v"(s3), "+v"(s4), "+v"(s5), "+v"(s6),     \
          "+v"(s7), "+v"(s8), "+v"(s9), "+v"(s10), "+v"(s11), "+v"(s12),            \
          "+v"(s13), "+v"(s14), "+v"(s15)::);                                       \
    uint32_t* wp_ = (uint32_t*)((char*)&ring[0] + (LH) + wconst                     \
                                + ((((CS) >> 1) & 63) << 2));                       \
    uint32_t a_, b_;                                                                \
    packw2(s0,  a_, b_); wp_[1042*0]  = a_; wp_[1042*0 + 1]  = b_;                  \
    packw2(s1,  a_, b_); wp_[1042*1]  = a_; wp_[1042*1 + 1]  = b_;                  \
    packw2(s2,  a_, b_); wp_[1042*2]  = a_; wp_[1042*2 + 1]  = b_;                  \
    packw2(s3,  a_, b_); wp_[1042*3]  = a_; wp_[1042*3 + 1]  = b_;                  \
    packw2(s4,  a_, b_); wp_[1042*4]  = a_; wp_[1042*4 + 1]  = b_;                  \
    packw2(s5,  a_, b_); wp_[1042*5]  = a_; wp_[1042*5 + 1]  = b_;                  \
    packw2(s6,  a_, b_); wp_[1042*6]  = a_; wp_[1042*6 + 1]  = b_;                  \
    packw2(s7,  a_, b_); wp_[1042*7]  = a_; wp_[1042*7 + 1]  = b_;                  \
    packw2(s8,  a_, b_); wp_[1042*8]  = a_; wp_[1042*8 + 1]  = b_;                  \
    packw2(s9,  a_, b_); wp_[1042*9]  = a_; wp_[1042*9 + 1]  = b_;                  \
    packw2(s10, a_, b_); wp_[1042*10] = a_; wp_[1042*10 + 1] = b_;                  \
    packw2(s11, a_, b_); wp_[1042*11] = a_; wp_[1042*11 + 1] = b_;                  \
    packw2(s12, a_, b_); wp_[1042*12] = a_; wp_[1042*12 + 1] = b_;                  \
    packw2(s13, a_, b_); wp_[1042*13] = a_; wp_[1042*13 + 1] = b_;                  \
    packw2(s14, a_, b_); wp_[1042*14] = a_; wp_[1042*14 + 1] = b_;                  \
    packw2(s15, a_, b_); wp_[1042*15] = a_; wp_[1042*15 + 1] = b_;                  \
} while (0)

__global__ __launch_bounds__(64, 1) void sdtw_kernel(const float* __restrict__ D,
                                                     float* __restrict__ out) {
  __shared__ uint32_t ring[64 * LS + 4];  // per-lane bf16 ring: 521 dwords/lane
  const int l = threadIdx.x;              // single wave: lane = 8-row strip
  const int b = blockIdx.x;

  u32x4 srd;  // raw buffer descriptor over D (OOB -> 0, never faults)
  const uint64_t base = (uint64_t)(const void*)D;
  srd[0] = (unsigned)base;
  srd[1] = (unsigned)(base >> 32) & 0xffffu;  // stride=0
  srd[2] = 64u * 512u * 512u * 4u;            // num_records (bytes)
  srd[3] = 0x00020000u;

  const bool par = (l & 1) != 0;
  const uint32_t shE = par ? 0u : 16u;
  const uint32_t shO = par ? 16u : 0u;
  // stage load base: row (l>>2) + col-sub (l&3)*4, batch b
  const int voBase = (b << 20) + ((l >> 2) << 11) + ((l & 3) << 4);
  // stage write base (byte): 2084*(l>>5) + 260*((l>>2)&7) + 8*(l&3)
  const int wconst = 2084 * (l >> 5) + 260 * ((l >> 2) & 7) + 8 * (l & 3);
  const uint32_t* __restrict__ rb = &ring[LS * l];

  float x[8] = {0, 0, 0, 0, 0, 0, 0, 0};  // P(left boundary INF) = 0
  float areg = 0.0f;                      // diag input for row 8l+1
  int E = 0;                              // per-lane scale exponent

  f4 s0, s1, s2, s3, s4, s5, s6, s7, s8, s9, s10, s11, s12, s13, s14, s15;

  // prologue: stage cols [0,16) for both row-halves (sequential, same regs)
  ISSUE(0, 0);
  WRITEB(0, 0);
  ISSUE(0, 524288);   // +256 rows (bytes)
  WRITEB(0, 66688);   // +32 owner lanes (bytes)

  for (int g = 0; g < NG; ++g) {
    const int t0 = 8 * g;
    // stage block [CS, CS+16): A-half (rows 0..255) on even g, B on odd g
    const int CS = (t0 & ~15) + 16;
    const bool doStage = (CS <= 496);
    const int HOFF = (g & 1) ? 524288 : 0;
    const int LH = (g & 1) ? 66688 : 0;
    if (doStage) ISSUE(CS, HOFF);

    // ring reads: 5 words x 8 rows covering cols [t0-l, t0-l+8]
    const int k0 = ((t0 - l) >> 1) & 63;  // arith shift: correct mod-128 ring idx
    uint32_t Wr[8][5];
#pragma unroll
    for (int k = 0; k < 5; ++k) {
      const int m = (k0 + k) & 63;
#pragma unroll
      for (int r = 0; r < 8; ++r) Wr[r][k] = rb[65 * r + m];
    }

    // per-lane scale maintenance (wave-local only)
    const int En = dpp_shr1_i(E);
    if ((x[0] == 0.0f) && (l != 0)) E = En;  // inactive: track left neighbor
    int dE = En - E;
    dE = dE < -126 ? -126 : (dE > 126 ? 126 : dE);
    const float rsc = __int_as_float((127 + dE) << 23);

    if (g < 8 || g >= 64)
      steps8<true>(Wr, t0, l, par, shE, shO, rsc, x, areg);
    else
      steps8<false>(Wr, t0, l, par, shE, shO, rsc, x, areg);

    // per-lane renorm: recenter max exponent to 2^-10
    int ex = 0;
#pragma unroll
    for (int r = 0; r < 8; ++r) ex = imax(ex, (__float_as_int(x[r]) >> 23) & 255);
    int sh = (ex > 0) ? (117 - ex) : 0;
    sh = sh < -110 ? -110 : sh;
    const float sc = __int_as_float((127 + sh) << 23);
#pragma unroll
    for (int r = 0; r < 8; ++r) x[r] *= sc;
    areg *= sc;
    E -= sh;

    if (doStage) WRITEB(CS, LH);
  }

  if (l == 63) {
    // x[7] * 2^E = exp(-R[512][512]);  v_log_f32 is log2
    const float Rv = -(__builtin_amdgcn_logf(x[7]) + (float)E);
    out[b] = Rv * LN2;
  }
}

extern "C" void kernel_launch(void* const* d_in, const int* in_sizes, int n_in,
                              void* d_out, int out_size, void* d_ws, size_t ws_size,
                              hipStream_t stream) {
  const float* D = (const float*)d_in[0];
  float* out = (float*)d_out;
  hipLaunchKernelGGL(sdtw_kernel, dim3(64), dim3(64), 0, stream, D, out);
}